// Round 5
// baseline (970.971 us; speedup 1.0000x reference)
//
#include <hip/hip_runtime.h>
#include <math.h>

#define EPS 1e-7f
#define IN1_ELEMS 26214400   // 256*20*20*256 (bf16 elements per plane)
#define BT_ELEMS  5308416    // 256*20736

typedef float fvec4 __attribute__((ext_vector_type(4)));
typedef short short8 __attribute__((ext_vector_type(8)));
typedef __bf16 bf16x8 __attribute__((ext_vector_type(8)));

__device__ inline unsigned short f2bf(float f){
  unsigned int u = __float_as_uint(f);
  unsigned int r = (u + 0x7fffu + ((u >> 16) & 1u)) >> 16;
  return (unsigned short)r;
}
__device__ inline float bf2f(unsigned short h){
  return __uint_as_float(((unsigned int)h) << 16);
}
__device__ inline void async16(unsigned short* dst, const unsigned short* src){
  __builtin_amdgcn_global_load_lds((const __attribute__((address_space(1))) void*)src,
                                   (__attribute__((address_space(3))) void*)dst, 16, 0, 0);
}
__device__ inline fvec4 mfma_bf16(short8 a, short8 b, fvec4 c){
  return __builtin_amdgcn_mfma_f32_16x16x32_bf16(
      __builtin_bit_cast(bf16x8, a), __builtin_bit_cast(bf16x8, b), c, 0, 0, 0);
}

// ---------------- K0: conv2_w -> BT^T (hi/lo bf16 split) + zero c2out ----------------
__global__ __launch_bounds__(256) void wt_kernel(const float* __restrict__ w2,
    unsigned short* __restrict__ BTh, unsigned short* __restrict__ BTl,
    float* __restrict__ c2out){
  __shared__ float tile[64][65];
  int t = threadIdx.x;
  int k0 = blockIdx.x * 64, oc0 = blockIdx.y * 64;
  int bid = blockIdx.y*324 + blockIdx.x;
  for (int g = bid*256 + t; g < 2359296; g += 1296*256) c2out[g] = 0.f;
  #pragma unroll
  for (int p = 0; p < 16; ++p){
    int f = p*256 + t;
    int kr = f >> 6, cc = f & 63;
    tile[kr][cc] = w2[(size_t)(k0 + kr)*256 + oc0 + cc];
  }
  __syncthreads();
  #pragma unroll
  for (int p = 0; p < 16; ++p){
    int f = p*256 + t;
    int ocr = f >> 6, kc = f & 63;
    float v = tile[kc][ocr];
    unsigned short h = f2bf(v);
    size_t idx = (size_t)(oc0 + ocr)*20736 + k0 + kc;
    BTh[idx] = h;
    BTl[idx] = f2bf(v - bf2f(h));
  }
}

// ---------------- K1: conv1 9x9 s1 + bias + relu -> bf16 hi/lo ----------------
__global__ __launch_bounds__(256) void conv1_kernel(const float* __restrict__ img,
    const float* __restrict__ w1, const float* __restrict__ b1,
    unsigned short* __restrict__ outh, unsigned short* __restrict__ outl){
  __shared__ float sim[252];
  int t = threadIdx.x;
  int oh = blockIdx.x, b = blockIdx.y;
  if (t < 252) sim[t] = img[((size_t)b*28 + oh + t/28)*28 + (t%28)];
  __syncthreads();
  float acc[20];
  #pragma unroll
  for (int i = 0; i < 20; ++i) acc[i] = 0.f;
  #pragma unroll
  for (int kh = 0; kh < 9; ++kh){
    float im[28];
    #pragma unroll
    for (int c = 0; c < 28; ++c) im[c] = sim[kh*28 + c];
    #pragma unroll
    for (int kw = 0; kw < 9; ++kw){
      float wv = w1[(kh*9 + kw)*256 + t];
      #pragma unroll
      for (int ow = 0; ow < 20; ++ow) acc[ow] = fmaf(im[ow + kw], wv, acc[ow]);
    }
  }
  float bv = b1[t];
  size_t base = ((size_t)(b*20 + oh))*20*256 + t;
  #pragma unroll
  for (int ow = 0; ow < 20; ++ow){
    float v = fmaxf(acc[ow] + bv, 0.f);
    unsigned short h = f2bf(v);
    outh[base + ow*256] = h;
    outl[base + ow*256] = f2bf(v - bf2f(h));
  }
}

// ---------------- K2: conv2 implicit GEMM, split-bf16 3-pass MFMA ----------------
// Double-buffered single-barrier pipeline: stage(next) issued right after the
// barrier; barrier's implicit vmcnt(0) drains loads issued one compute-phase
// earlier -> global latency hidden. Staging lanes row-major (coalesced 64B per
// 4 lanes); LDS position swizzled pos = seg ^ ((row>>1)&3) so fragment
// ds_read_b128 is 2-way-only (free) instead of the R2 4-way pattern.
__global__ __launch_bounds__(256) void conv2_mfma(const unsigned short* __restrict__ in1h,
    const unsigned short* __restrict__ BTh, float* __restrict__ out){
  __shared__ __align__(16) unsigned short lds[32768]; // 2 bufs x (Ah|Al|Bh|Bl 4096 shorts each)
  const int t = threadIdx.x;
  const int lane = t & 63, w = t >> 6;
  const int m0 = blockIdx.y * 128, n0 = blockIdx.x * 128;
  // staging: lane t -> row t>>2 (+64*h), LDS pos t&3, fetch seg q = (t&3)^((t>>3)&3)
  const int rowA = t >> 2, q = (t & 3) ^ ((t >> 3) & 3);

  const unsigned short* aS[2];
  const unsigned short* bS[2];
  #pragma unroll
  for (int h = 0; h < 2; ++h){
    int m = m0 + h*64 + rowA;
    int bb = m / 36, s = m - bb*36, oh = s / 6, ow = s - oh*6;
    aS[h] = in1h + ((size_t)((bb*20 + 2*oh)*20 + 2*ow))*256 + q*8;
    int n = n0 + h*64 + rowA;
    bS[h] = BTh + (size_t)n*20736 + q*8;
  }

  // fragment read: lane wants (row r=lane&15 within tile, seg=lane>>4) -> pos = seg^((r>>1)&3)
  const int r = lane & 15;
  const int p = (lane >> 4) ^ ((lane >> 1) & 3);
  int roA[4], roB[4];
  #pragma unroll
  for (int i=0;i<4;++i){
    roA[i] = ((w >> 1)*64 + i*16 + r)*32 + p*8;
    roB[i] = ((w & 1)*64  + i*16 + r)*32 + p*8;
  }

  fvec4 acc[4][4];
  #pragma unroll
  for (int i=0;i<4;++i)
    #pragma unroll
    for (int j=0;j<4;++j) acc[i][j] = (fvec4){0.f,0.f,0.f,0.f};

  const int ks0 = blockIdx.z * 81;

  #define STAGE(BUF, KS) do{                                            \
    int kk_ = (KS) >> 3, kh_ = kk_/9, kw_ = kk_ - kh_*9;                \
    int aoff_ = (kh_*20 + kw_)*256 + ((KS) & 7)*32;                     \
    int boff_ = (KS)*32;                                                \
    int base_ = (BUF) << 14;                                            \
    _Pragma("unroll")                                                   \
    for (int h_=0; h_<2; ++h_){                                         \
      async16(&lds[base_ +         h_*2048 + t*8], aS[h_] + aoff_);     \
      async16(&lds[base_ + 4096  + h_*2048 + t*8], aS[h_] + IN1_ELEMS + aoff_); \
      async16(&lds[base_ + 8192  + h_*2048 + t*8], bS[h_] + boff_);     \
      async16(&lds[base_ + 12288 + h_*2048 + t*8], bS[h_] + BT_ELEMS + boff_);  \
    } }while(0)

  STAGE(0, ks0);
  int buf = 0;
  for (int it = 0; it < 81; ++it){
    __syncthreads();                      // drains prev stage (one compute old); all done reading buf^1
    if (it < 80) STAGE(buf^1, ks0 + it + 1);
    int base = buf << 14;
    short8 ah[4], al[4], bh[4], bl[4];
    #pragma unroll
    for (int i=0;i<4;++i){
      ah[i] = *(const short8*)&lds[base + roA[i]];
      al[i] = *(const short8*)&lds[base + 4096 + roA[i]];
      bh[i] = *(const short8*)&lds[base + 8192 + roB[i]];
      bl[i] = *(const short8*)&lds[base + 12288 + roB[i]];
    }
    #pragma unroll
    for (int i=0;i<4;++i)
      #pragma unroll
      for (int j=0;j<4;++j){
        acc[i][j] = mfma_bf16(ah[i], bh[j], acc[i][j]);
        acc[i][j] = mfma_bf16(ah[i], bl[j], acc[i][j]);
        acc[i][j] = mfma_bf16(al[i], bh[j], acc[i][j]);
      }
    buf ^= 1;
  }

  const int qm = (w >> 1)*64, qn = (w & 1)*64;
  #pragma unroll
  for (int i=0;i<4;++i){
    int gm = m0 + qm + i*16 + ((lane >> 4) << 2);
    #pragma unroll
    for (int j=0;j<4;++j){
      int gn = n0 + qn + j*16 + (lane & 15);
      #pragma unroll
      for (int rr=0;rr<4;++rr)
        atomicAdd(&out[(size_t)(gm + rr)*256 + gn], acc[i][j][rr]);
    }
  }
}

// ---------------- K3: bias + relu + squash -> pc ; + zero s1/s2 ----------------
__global__ __launch_bounds__(256) void squash_pc_kernel(const float* __restrict__ c2out,
    const float* __restrict__ b2, float* __restrict__ pc, float* __restrict__ s1s2){
  int g = blockIdx.x*256 + threadIdx.x;   // 294912 capsules
  if (g < 81920) s1s2[g] = 0.f;           // zero s1+s2 (contiguous) before atomics
  const float* s = c2out + (size_t)g*8;
  int oc0 = (g & 31) * 8;
  float v[8], sq = 0.f;
  #pragma unroll
  for (int e=0;e<8;++e){ float x = fmaxf(s[e] + b2[oc0+e], 0.f); v[e] = x; sq += x*x; }
  float fac = sq / ((1.f + sq) * sqrtf(sq + EPS));
  float* o = pc + (size_t)g*8;
  #pragma unroll
  for (int e=0;e<8;++e) o[e] = v[e]*fac;
}

// ---------------- K4a: s1 partials only (u_hat recomputed later, never stored) --------
__global__ __launch_bounds__(256) void s1_producer(const float* __restrict__ pc,
    const float* __restrict__ Wm, float* __restrict__ s1){
  __shared__ float pcl[2048]; // [16 b][16 n][8 i]
  int t = threadIdx.x;
  int n0 = blockIdx.x * 16, b0 = blockIdx.y * 16;
  #pragma unroll
  for (int p = 0; p < 8; ++p){
    int f = p*256 + t;
    int bl = f >> 7, rem = f & 127;
    pcl[f] = pc[((size_t)(b0 + bl)*1152 + n0)*8 + rem];
  }
  __syncthreads();
  for (int r = 0; r < 10; ++r){
    int item = r*256 + t;               // (b_local, cj)
    int bl = item / 160, cj = item - bl*160;
    float s1a = 0.f;
    const float* pb = &pcl[bl*128];
    #pragma unroll 4
    for (int nl = 0; nl < 16; ++nl){
      const float4* wp = (const float4*)&Wm[((size_t)(n0 + nl)*160 + cj)*8];
      float4 w0 = wp[0], w1 = wp[1];
      const float4* pp = (const float4*)&pb[nl*8];
      float4 p0 = pp[0], p1 = pp[1];
      s1a += w0.x*p0.x + w0.y*p0.y + w0.z*p0.z + w0.w*p0.w
           + w1.x*p1.x + w1.y*p1.y + w1.z*p1.z + w1.w*p1.w;
    }
    atomicAdd(&s1[(b0 + bl)*160 + cj], s1a);
  }
}

// ---------------- K4b: fused routing: recompute u_hat -> uv -> softmax -> s2 ----------
// block = 320 threads (nl 0..31 x c 0..9), covers 8 batches x 32 n-capsules.
__global__ __launch_bounds__(320) void routing2(const float* __restrict__ pc,
    const float* __restrict__ Wm, const float* __restrict__ s1, float* __restrict__ s2){
  __shared__ float pcl[32][64];     // [nl][b*8+i]
  __shared__ float v1l[8][160];
  __shared__ float facl[80];
  __shared__ float uvl[32][10][8];  // [nl][c][b]; reused as c2 after softmax
  __shared__ float s2l[8][160];
  const int t = threadIdx.x;
  const int n0 = blockIdx.x*32, b0 = blockIdx.y*8;

  for (int f = t; f < 2048; f += 320){
    int b = f >> 8, rem = f & 255;            // rem = nl*8+i
    pcl[rem >> 3][b*8 + (rem & 7)] =
        pc[((size_t)(b0 + b)*1152 + n0 + (rem >> 3))*8 + (rem & 7)];
  }
  if (t < 80){
    int b = t/10, c = t - (t/10)*10;
    const float* s = s1 + (size_t)(b0 + b)*160 + c*16;
    float sq = 0.f;
    #pragma unroll
    for (int j=0;j<16;++j){ float v = s[j]*0.1f; sq += v*v; }
    facl[t] = 0.1f * sq / ((1.f + sq) * sqrtf(sq + EPS));
  }
  for (int f = t; f < 1280; f += 320) ((float*)s2l)[f] = 0.f;
  __syncthreads();
  for (int f = t; f < 1280; f += 320){
    int b = f / 160, cj = f - b*160;
    v1l[b][cj] = s1[(size_t)(b0 + b)*160 + cj] * facl[b*10 + (cj >> 4)];
  }
  __syncthreads();

  const int nl = t / 10, c = t - (t/10)*10;
  float pcr[64];
  #pragma unroll
  for (int u = 0; u < 16; ++u) ((float4*)pcr)[u] = ((const float4*)&pcl[nl][0])[u];
  const float* wrow = Wm + ((size_t)(n0 + nl)*160 + c*16)*8;   // 128 floats [j][i]

  float uv[8];
  #pragma unroll
  for (int b=0;b<8;++b) uv[b] = 0.f;
  #pragma unroll
  for (int j = 0; j < 16; ++j){
    float4 w0 = ((const float4*)wrow)[j*2], w1 = ((const float4*)wrow)[j*2+1];
    #pragma unroll
    for (int b=0;b<8;++b){
      float tj = w0.x*pcr[b*8+0] + w0.y*pcr[b*8+1] + w0.z*pcr[b*8+2] + w0.w*pcr[b*8+3]
               + w1.x*pcr[b*8+4] + w1.y*pcr[b*8+5] + w1.z*pcr[b*8+6] + w1.w*pcr[b*8+7];
      uv[b] = fmaf(tj, v1l[b][c*16 + j], uv[b]);
    }
  }
  #pragma unroll
  for (int b=0;b<8;++b) uvl[nl][c][b] = uv[b];
  __syncthreads();

  if (t < 256){
    int snl = t >> 3, sb = t & 7;
    float mx = uvl[snl][0][sb];
    #pragma unroll
    for (int cc=1;cc<10;++cc) mx = fmaxf(mx, uvl[snl][cc][sb]);
    float e[10], sum = 0.f;
    #pragma unroll
    for (int cc=0;cc<10;++cc){ e[cc] = expf(uvl[snl][cc][sb] - mx); sum += e[cc]; }
    float inv = 1.f/sum;
    #pragma unroll
    for (int cc=0;cc<10;++cc) uvl[snl][cc][sb] = e[cc]*inv;
  }
  __syncthreads();

  float c2r[8];
  #pragma unroll
  for (int b=0;b<8;++b) c2r[b] = uvl[nl][c][b];
  #pragma unroll
  for (int j = 0; j < 16; ++j){
    float4 w0 = ((const float4*)wrow)[j*2], w1 = ((const float4*)wrow)[j*2+1];
    #pragma unroll
    for (int b=0;b<8;++b){
      float uh = w0.x*pcr[b*8+0] + w0.y*pcr[b*8+1] + w0.z*pcr[b*8+2] + w0.w*pcr[b*8+3]
               + w1.x*pcr[b*8+4] + w1.y*pcr[b*8+5] + w1.z*pcr[b*8+6] + w1.w*pcr[b*8+7];
      atomicAdd(&s2l[b][c*16 + j], c2r[b]*uh);
    }
  }
  __syncthreads();
  for (int f = t; f < 1280; f += 320){
    int b = f / 160, cj = f - b*160;
    atomicAdd(&s2[(size_t)(b0 + b)*160 + cj], s2l[b][cj]);
  }
}

// ---------------- K4d: v2, norms, argmax, mask ----------------
__global__ __launch_bounds__(64) void finalize_kernel(const float* __restrict__ s2,
    const int* __restrict__ target, float* __restrict__ out_norm,
    float* __restrict__ out_pred, float* __restrict__ masked){
  __shared__ float v2l[160];
  __shared__ float nrm[10];
  int b = blockIdx.x, t = threadIdx.x;
  if (t < 10){
    const float* s = s2 + b*160 + t*16;
    float x[16], sq = 0.f;
    #pragma unroll
    for (int j=0;j<16;++j){ x[j] = s[j]; sq += x[j]*x[j]; }
    float fac = sq / ((1.f + sq) * sqrtf(sq + EPS));
    float n2 = 0.f;
    #pragma unroll
    for (int j=0;j<16;++j){ float v = x[j]*fac; v2l[t*16+j] = v; n2 += v*v; }
    float nr = sqrtf(n2 + EPS);
    nrm[t] = nr;
    out_norm[b*10 + t] = nr;
  }
  __syncthreads();
  if (t == 0){
    int am = 0; float bv = nrm[0];
    #pragma unroll
    for (int c=1;c<10;++c) if (nrm[c] > bv){ bv = nrm[c]; am = c; }
    out_pred[b] = (float)am;
  }
  int tg = target[b];
  #pragma unroll
  for (int p = 0; p < 3; ++p){
    int cj = p*64 + t;
    if (cj < 160) masked[b*160 + cj] = ((cj >> 4) == tg) ? v2l[cj] : 0.f;
  }
}

// ---------------- decoder GEMMs (M=256 fixed) ----------------
__global__ __launch_bounds__(256) void dec_gemm(const float* __restrict__ A,
    const float* __restrict__ B, const float* __restrict__ bias, float* __restrict__ C,
    int K, int N, int act){
  int t = threadIdx.x;
  int n = blockIdx.x*64 + (t & 63);
  int m = blockIdx.y*4 + (t >> 6);
  if (n >= N) return;
  float acc = 0.f;
  const float* a = A + (size_t)m*K;
  const float* bp = B + n;
  #pragma unroll 8
  for (int k = 0; k < K; ++k) acc = fmaf(a[k], bp[(size_t)k*N], acc);
  acc += bias[n];
  if (act == 0) acc = fmaxf(acc, 0.f);
  else acc = 1.f/(1.f + expf(-acc));
  C[(size_t)m*N + n] = acc;
}

extern "C" void kernel_launch(void* const* d_in, const int* in_sizes, int n_in,
                              void* d_out, int out_size, void* d_ws, size_t ws_size,
                              hipStream_t stream) {
  const float* image   = (const float*)d_in[0];
  const int*   target  = (const int*)d_in[1];
  const float* conv1_w = (const float*)d_in[2];
  const float* conv1_b = (const float*)d_in[3];
  const float* conv2_w = (const float*)d_in[4];
  const float* conv2_b = (const float*)d_in[5];
  const float* Wm      = (const float*)d_in[6];
  const float* d1_w    = (const float*)d_in[7];
  const float* d1_b    = (const float*)d_in[8];
  const float* d2_w    = (const float*)d_in[9];
  const float* d2_b    = (const float*)d_in[10];
  const float* d3_w    = (const float*)d_in[11];
  const float* d3_b    = (const float*)d_in[12];

  char* ws = (char*)d_ws;
  unsigned short* in1h = (unsigned short*)(ws);               // +IN1_ELEMS: in1l
  unsigned short* BTh  = (unsigned short*)(ws + 104857600);   // +BT_ELEMS: BTl
  float* c2out  = (float*)(ws + 126091264);                   // 9437184 B
  float* pc     = (float*)(ws + 135528448);                   // 9437184 B
  float* s1     = (float*)(ws + 144965632);                   // 163840 B
  float* s2     = (float*)(ws + 145129472);                   // 163840 B (contiguous after s1)
  float* masked = (float*)(ws + 145293312);                   // 163840 B
  float* h1     = (float*)(ws + 145457152);                   // 524288 B
  float* h2     = (float*)(ws + 145981440);                   // 1048576 B

  float* out_norm = (float*)d_out;            // 2560
  float* out_pred = out_norm + 2560;          // 256
  float* dec      = out_norm + 2816;          // 200704

  wt_kernel<<<dim3(324,4),256,0,stream>>>(conv2_w, BTh, BTh + BT_ELEMS, c2out);
  conv1_kernel<<<dim3(20,256),256,0,stream>>>(image, conv1_w, conv1_b, in1h, in1h + IN1_ELEMS);
  conv2_mfma<<<dim3(2,72,8),256,0,stream>>>(in1h, BTh, c2out);
  squash_pc_kernel<<<dim3(1152),256,0,stream>>>(c2out, conv2_b, pc, s1);
  s1_producer<<<dim3(72,16),256,0,stream>>>(pc, Wm, s1);
  routing2<<<dim3(36,32),320,0,stream>>>(pc, Wm, s1, s2);
  finalize_kernel<<<dim3(256),64,0,stream>>>(s2, target, out_norm, out_pred, masked);
  dec_gemm<<<dim3(8,64),256,0,stream>>>(masked, d1_w, d1_b, h1, 160, 512, 0);
  dec_gemm<<<dim3(16,64),256,0,stream>>>(h1, d2_w, d2_b, h2, 512, 1024, 0);
  dec_gemm<<<dim3(13,64),256,0,stream>>>(h2, d3_w, d3_b, dec, 1024, 784, 1);
}

// Round 6
// 736.698 us; speedup vs baseline: 1.3180x; 1.3180x over previous
//
#include <hip/hip_runtime.h>
#include <math.h>

#define EPS 1e-7f
#define IN1_ELEMS 26214400   // 256*20*20*256 (bf16 elements per plane)
#define BT_ELEMS  5308416    // 256*20736

typedef float fvec4 __attribute__((ext_vector_type(4)));
typedef short short8 __attribute__((ext_vector_type(8)));
typedef __bf16 bf16x8 __attribute__((ext_vector_type(8)));

__device__ inline unsigned short f2bf(float f){
  unsigned int u = __float_as_uint(f);
  unsigned int r = (u + 0x7fffu + ((u >> 16) & 1u)) >> 16;
  return (unsigned short)r;
}
__device__ inline float bf2f(unsigned short h){
  return __uint_as_float(((unsigned int)h) << 16);
}
__device__ inline void async16(unsigned short* dst, const unsigned short* src){
  __builtin_amdgcn_global_load_lds((const __attribute__((address_space(1))) void*)src,
                                   (__attribute__((address_space(3))) void*)dst, 16, 0, 0);
}
__device__ inline fvec4 mfma_bf16(short8 a, short8 b, fvec4 c){
  return __builtin_amdgcn_mfma_f32_16x16x32_bf16(
      __builtin_bit_cast(bf16x8, a), __builtin_bit_cast(bf16x8, b), c, 0, 0, 0);
}

// ---------------- K0: conv2_w -> BT^T (hi/lo bf16 split) + zero c2out ----------------
__global__ __launch_bounds__(256) void wt_kernel(const float* __restrict__ w2,
    unsigned short* __restrict__ BTh, unsigned short* __restrict__ BTl,
    float* __restrict__ c2out){
  __shared__ float tile[64][65];
  int t = threadIdx.x;
  int k0 = blockIdx.x * 64, oc0 = blockIdx.y * 64;
  int bid = blockIdx.y*324 + blockIdx.x;
  for (int g = bid*256 + t; g < 2359296; g += 1296*256) c2out[g] = 0.f;
  #pragma unroll
  for (int p = 0; p < 16; ++p){
    int f = p*256 + t;
    int kr = f >> 6, cc = f & 63;
    tile[kr][cc] = w2[(size_t)(k0 + kr)*256 + oc0 + cc];
  }
  __syncthreads();
  #pragma unroll
  for (int p = 0; p < 16; ++p){
    int f = p*256 + t;
    int ocr = f >> 6, kc = f & 63;
    float v = tile[kc][ocr];
    unsigned short h = f2bf(v);
    size_t idx = (size_t)(oc0 + ocr)*20736 + k0 + kc;
    BTh[idx] = h;
    BTl[idx] = f2bf(v - bf2f(h));
  }
}

// ---------------- K1: conv1 9x9 s1 + bias + relu -> bf16 hi/lo ----------------
__global__ __launch_bounds__(256) void conv1_kernel(const float* __restrict__ img,
    const float* __restrict__ w1, const float* __restrict__ b1,
    unsigned short* __restrict__ outh, unsigned short* __restrict__ outl){
  __shared__ float sim[252];
  int t = threadIdx.x;
  int oh = blockIdx.x, b = blockIdx.y;
  if (t < 252) sim[t] = img[((size_t)b*28 + oh + t/28)*28 + (t%28)];
  __syncthreads();
  float acc[20];
  #pragma unroll
  for (int i = 0; i < 20; ++i) acc[i] = 0.f;
  #pragma unroll
  for (int kh = 0; kh < 9; ++kh){
    float im[28];
    #pragma unroll
    for (int c = 0; c < 28; ++c) im[c] = sim[kh*28 + c];
    #pragma unroll
    for (int kw = 0; kw < 9; ++kw){
      float wv = w1[(kh*9 + kw)*256 + t];
      #pragma unroll
      for (int ow = 0; ow < 20; ++ow) acc[ow] = fmaf(im[ow + kw], wv, acc[ow]);
    }
  }
  float bv = b1[t];
  size_t base = ((size_t)(b*20 + oh))*20*256 + t;
  #pragma unroll
  for (int ow = 0; ow < 20; ++ow){
    float v = fmaxf(acc[ow] + bv, 0.f);
    unsigned short h = f2bf(v);
    outh[base + ow*256] = h;
    outl[base + ow*256] = f2bf(v - bf2f(h));
  }
}

// ---------------- K2: conv2 implicit GEMM, split-bf16 3-pass MFMA ----------------
// Double-buffered single-barrier pipeline (R5). Staging row-major lanes,
// XOR-swizzled LDS positions -> fragment ds_read_b128 2-way-only.
__global__ __launch_bounds__(256) void conv2_mfma(const unsigned short* __restrict__ in1h,
    const unsigned short* __restrict__ BTh, float* __restrict__ out){
  __shared__ __align__(16) unsigned short lds[32768]; // 2 bufs x (Ah|Al|Bh|Bl 4096 shorts each)
  const int t = threadIdx.x;
  const int lane = t & 63, w = t >> 6;
  const int m0 = blockIdx.y * 128, n0 = blockIdx.x * 128;
  const int rowA = t >> 2, q = (t & 3) ^ ((t >> 3) & 3);

  const unsigned short* aS[2];
  const unsigned short* bS[2];
  #pragma unroll
  for (int h = 0; h < 2; ++h){
    int m = m0 + h*64 + rowA;
    int bb = m / 36, s = m - bb*36, oh = s / 6, ow = s - oh*6;
    aS[h] = in1h + ((size_t)((bb*20 + 2*oh)*20 + 2*ow))*256 + q*8;
    int n = n0 + h*64 + rowA;
    bS[h] = BTh + (size_t)n*20736 + q*8;
  }

  const int r = lane & 15;
  const int p = (lane >> 4) ^ ((lane >> 1) & 3);
  int roA[4], roB[4];
  #pragma unroll
  for (int i=0;i<4;++i){
    roA[i] = ((w >> 1)*64 + i*16 + r)*32 + p*8;
    roB[i] = ((w & 1)*64  + i*16 + r)*32 + p*8;
  }

  fvec4 acc[4][4];
  #pragma unroll
  for (int i=0;i<4;++i)
    #pragma unroll
    for (int j=0;j<4;++j) acc[i][j] = (fvec4){0.f,0.f,0.f,0.f};

  const int ks0 = blockIdx.z * 81;

  #define STAGE(BUF, KS) do{                                            \
    int kk_ = (KS) >> 3, kh_ = kk_/9, kw_ = kk_ - kh_*9;                \
    int aoff_ = (kh_*20 + kw_)*256 + ((KS) & 7)*32;                     \
    int boff_ = (KS)*32;                                                \
    int base_ = (BUF) << 14;                                            \
    _Pragma("unroll")                                                   \
    for (int h_=0; h_<2; ++h_){                                         \
      async16(&lds[base_ +         h_*2048 + t*8], aS[h_] + aoff_);     \
      async16(&lds[base_ + 4096  + h_*2048 + t*8], aS[h_] + IN1_ELEMS + aoff_); \
      async16(&lds[base_ + 8192  + h_*2048 + t*8], bS[h_] + boff_);     \
      async16(&lds[base_ + 12288 + h_*2048 + t*8], bS[h_] + BT_ELEMS + boff_);  \
    } }while(0)

  STAGE(0, ks0);
  int buf = 0;
  for (int it = 0; it < 81; ++it){
    __syncthreads();
    if (it < 80) STAGE(buf^1, ks0 + it + 1);
    int base = buf << 14;
    short8 ah[4], al[4], bh[4], bl[4];
    #pragma unroll
    for (int i=0;i<4;++i){
      ah[i] = *(const short8*)&lds[base + roA[i]];
      al[i] = *(const short8*)&lds[base + 4096 + roA[i]];
      bh[i] = *(const short8*)&lds[base + 8192 + roB[i]];
      bl[i] = *(const short8*)&lds[base + 12288 + roB[i]];
    }
    #pragma unroll
    for (int i=0;i<4;++i)
      #pragma unroll
      for (int j=0;j<4;++j){
        acc[i][j] = mfma_bf16(ah[i], bh[j], acc[i][j]);
        acc[i][j] = mfma_bf16(ah[i], bl[j], acc[i][j]);
        acc[i][j] = mfma_bf16(al[i], bh[j], acc[i][j]);
      }
    buf ^= 1;
  }

  const int qm = (w >> 1)*64, qn = (w & 1)*64;
  #pragma unroll
  for (int i=0;i<4;++i){
    int gm = m0 + qm + i*16 + ((lane >> 4) << 2);
    #pragma unroll
    for (int j=0;j<4;++j){
      int gn = n0 + qn + j*16 + (lane & 15);
      #pragma unroll
      for (int rr=0;rr<4;++rr)
        atomicAdd(&out[(size_t)(gm + rr)*256 + gn], acc[i][j][rr]);
    }
  }
}

// ---------------- K3: bias + relu + squash -> pc ; + zero s1/s2 ----------------
__global__ __launch_bounds__(256) void squash_pc_kernel(const float* __restrict__ c2out,
    const float* __restrict__ b2, float* __restrict__ pc, float* __restrict__ s1s2){
  int g = blockIdx.x*256 + threadIdx.x;   // 294912 capsules
  if (g < 81920) s1s2[g] = 0.f;           // zero s1+s2 (contiguous) before atomics
  const float* s = c2out + (size_t)g*8;
  int oc0 = (g & 31) * 8;
  float v[8], sq = 0.f;
  #pragma unroll
  for (int e=0;e<8;++e){ float x = fmaxf(s[e] + b2[oc0+e], 0.f); v[e] = x; sq += x*x; }
  float fac = sq / ((1.f + sq) * sqrtf(sq + EPS));
  float* o = pc + (size_t)g*8;
  #pragma unroll
  for (int e=0;e<8;++e) o[e] = v[e]*fac;
}

// ---------------- K4a: s1 partials only (u_hat recomputed later, never stored) --------
__global__ __launch_bounds__(256) void s1_producer(const float* __restrict__ pc,
    const float* __restrict__ Wm, float* __restrict__ s1){
  __shared__ float pcl[2048]; // [16 b][16 n][8 i]
  int t = threadIdx.x;
  int n0 = blockIdx.x * 16, b0 = blockIdx.y * 16;
  #pragma unroll
  for (int p = 0; p < 8; ++p){
    int f = p*256 + t;
    int bl = f >> 7, rem = f & 127;
    pcl[f] = pc[((size_t)(b0 + bl)*1152 + n0)*8 + rem];
  }
  __syncthreads();
  for (int r = 0; r < 10; ++r){
    int item = r*256 + t;               // (b_local, cj)
    int bl = item / 160, cj = item - bl*160;
    float s1a = 0.f;
    const float* pb = &pcl[bl*128];
    #pragma unroll 4
    for (int nl = 0; nl < 16; ++nl){
      const float4* wp = (const float4*)&Wm[((size_t)(n0 + nl)*160 + cj)*8];
      float4 w0 = wp[0], w1 = wp[1];
      const float4* pp = (const float4*)&pb[nl*8];
      float4 p0 = pp[0], p1 = pp[1];
      s1a += w0.x*p0.x + w0.y*p0.y + w0.z*p0.z + w0.w*p0.w
           + w1.x*p1.x + w1.y*p1.y + w1.z*p1.z + w1.w*p1.w;
    }
    atomicAdd(&s1[(b0 + bl)*160 + cj], s1a);
  }
}

// ---------------- K4b: fused routing: recompute u_hat -> uv -> softmax -> s2 ----------
// block = 320 threads, covers 8 batches x 32 n-capsules. NO LDS atomics:
// pass1 thread=(nl,c) computes uv; pass3 thread=(b-quad,cj) owns its s2 entries.
__global__ __launch_bounds__(320) void routing2(const float* __restrict__ pc,
    const float* __restrict__ Wm, const float* __restrict__ s1, float* __restrict__ s2){
  __shared__ float pcl[32][64];     // [nl][b*8+i]
  __shared__ float v1l[8][160];
  __shared__ float facl[80];
  __shared__ float c2l[32][10][8];  // [nl][c][b]: uv, then softmax'd c2
  const int t = threadIdx.x;
  const int n0 = blockIdx.x*32, b0 = blockIdx.y*8;

  for (int f = t; f < 2048; f += 320){
    int b = f >> 8, rem = f & 255;            // rem = nl*8+i
    pcl[rem >> 3][b*8 + (rem & 7)] =
        pc[((size_t)(b0 + b)*1152 + n0 + (rem >> 3))*8 + (rem & 7)];
  }
  if (t < 80){
    int b = t/10, c = t - (t/10)*10;
    const float* s = s1 + (size_t)(b0 + b)*160 + c*16;
    float sq = 0.f;
    #pragma unroll
    for (int j=0;j<16;++j){ float v = s[j]*0.1f; sq += v*v; }
    facl[t] = 0.1f * sq / ((1.f + sq) * sqrtf(sq + EPS));
  }
  __syncthreads();
  for (int f = t; f < 1280; f += 320){
    int b = f / 160, cj = f - b*160;
    v1l[b][cj] = s1[(size_t)(b0 + b)*160 + cj] * facl[b*10 + (cj >> 4)];
  }
  __syncthreads();

  // ---- pass 1: uv.  thread = (nl, c) ----
  {
    const int nl = t / 10, c = t - (t/10)*10;
    float pcr[64];
    #pragma unroll
    for (int u = 0; u < 16; ++u) ((float4*)pcr)[u] = ((const float4*)&pcl[nl][0])[u];
    const float* wrow = Wm + ((size_t)(n0 + nl)*160 + c*16)*8;
    float uv[8];
    #pragma unroll
    for (int b=0;b<8;++b) uv[b] = 0.f;
    #pragma unroll
    for (int j = 0; j < 16; ++j){
      float4 w0 = ((const float4*)wrow)[j*2], w1 = ((const float4*)wrow)[j*2+1];
      #pragma unroll
      for (int b=0;b<8;++b){
        float tj = w0.x*pcr[b*8+0] + w0.y*pcr[b*8+1] + w0.z*pcr[b*8+2] + w0.w*pcr[b*8+3]
                 + w1.x*pcr[b*8+4] + w1.y*pcr[b*8+5] + w1.z*pcr[b*8+6] + w1.w*pcr[b*8+7];
        uv[b] = fmaf(tj, v1l[b][c*16 + j], uv[b]);
      }
    }
    #pragma unroll
    for (int b=0;b<8;++b) c2l[nl][c][b] = uv[b];
  }
  __syncthreads();

  // ---- softmax over c: thread = (nl, b) ----
  if (t < 256){
    int snl = t >> 3, sb = t & 7;
    float mx = c2l[snl][0][sb];
    #pragma unroll
    for (int cc=1;cc<10;++cc) mx = fmaxf(mx, c2l[snl][cc][sb]);
    float e[10], sum = 0.f;
    #pragma unroll
    for (int cc=0;cc<10;++cc){ e[cc] = expf(c2l[snl][cc][sb] - mx); sum += e[cc]; }
    float inv = 1.f/sum;
    #pragma unroll
    for (int cc=0;cc<10;++cc) c2l[snl][cc][sb] = e[cc]*inv;
  }
  __syncthreads();

  // ---- pass 3: s2.  thread = (b-quad g, cj); owns 4 accumulators, zero LDS atomics ----
  {
    const int g = t / 160, cj = t - g*160;   // g in {0,1}
    const int c = cj >> 4;
    float acc0 = 0.f, acc1 = 0.f, acc2 = 0.f, acc3 = 0.f;
    for (int nl = 0; nl < 32; ++nl){
      const float4* wp = (const float4*)&Wm[((size_t)(n0 + nl)*160 + cj)*8];
      float4 w0 = wp[0], w1 = wp[1];
      const float* pb = &pcl[nl][g*32];
      const float* cc = &c2l[nl][c][g*4];
      float4 p0, p1;
      p0 = ((const float4*)pb)[0]; p1 = ((const float4*)pb)[1];
      acc0 = fmaf(cc[0], w0.x*p0.x + w0.y*p0.y + w0.z*p0.z + w0.w*p0.w
                       + w1.x*p1.x + w1.y*p1.y + w1.z*p1.z + w1.w*p1.w, acc0);
      p0 = ((const float4*)pb)[2]; p1 = ((const float4*)pb)[3];
      acc1 = fmaf(cc[1], w0.x*p0.x + w0.y*p0.y + w0.z*p0.z + w0.w*p0.w
                       + w1.x*p1.x + w1.y*p1.y + w1.z*p1.z + w1.w*p1.w, acc1);
      p0 = ((const float4*)pb)[4]; p1 = ((const float4*)pb)[5];
      acc2 = fmaf(cc[2], w0.x*p0.x + w0.y*p0.y + w0.z*p0.z + w0.w*p0.w
                       + w1.x*p1.x + w1.y*p1.y + w1.z*p1.z + w1.w*p1.w, acc2);
      p0 = ((const float4*)pb)[6]; p1 = ((const float4*)pb)[7];
      acc3 = fmaf(cc[3], w0.x*p0.x + w0.y*p0.y + w0.z*p0.z + w0.w*p0.w
                       + w1.x*p1.x + w1.y*p1.y + w1.z*p1.z + w1.w*p1.w, acc3);
    }
    atomicAdd(&s2[(size_t)(b0 + g*4 + 0)*160 + cj], acc0);
    atomicAdd(&s2[(size_t)(b0 + g*4 + 1)*160 + cj], acc1);
    atomicAdd(&s2[(size_t)(b0 + g*4 + 2)*160 + cj], acc2);
    atomicAdd(&s2[(size_t)(b0 + g*4 + 3)*160 + cj], acc3);
  }
}

// ---------------- K4d: v2, norms, argmax, mask ----------------
__global__ __launch_bounds__(64) void finalize_kernel(const float* __restrict__ s2,
    const int* __restrict__ target, float* __restrict__ out_norm,
    float* __restrict__ out_pred, float* __restrict__ masked){
  __shared__ float v2l[160];
  __shared__ float nrm[10];
  int b = blockIdx.x, t = threadIdx.x;
  if (t < 10){
    const float* s = s2 + b*160 + t*16;
    float x[16], sq = 0.f;
    #pragma unroll
    for (int j=0;j<16;++j){ x[j] = s[j]; sq += x[j]*x[j]; }
    float fac = sq / ((1.f + sq) * sqrtf(sq + EPS));
    float n2 = 0.f;
    #pragma unroll
    for (int j=0;j<16;++j){ float v = x[j]*fac; v2l[t*16+j] = v; n2 += v*v; }
    float nr = sqrtf(n2 + EPS);
    nrm[t] = nr;
    out_norm[b*10 + t] = nr;
  }
  __syncthreads();
  if (t == 0){
    int am = 0; float bv = nrm[0];
    #pragma unroll
    for (int c=1;c<10;++c) if (nrm[c] > bv){ bv = nrm[c]; am = c; }
    out_pred[b] = (float)am;
  }
  int tg = target[b];
  #pragma unroll
  for (int p = 0; p < 3; ++p){
    int cj = p*64 + t;
    if (cj < 160) masked[b*160 + cj] = ((cj >> 4) == tg) ? v2l[cj] : 0.f;
  }
}

// ---------------- decoder GEMMs (M=256 fixed) ----------------
__global__ __launch_bounds__(256) void dec_gemm(const float* __restrict__ A,
    const float* __restrict__ B, const float* __restrict__ bias, float* __restrict__ C,
    int K, int N, int act){
  int t = threadIdx.x;
  int n = blockIdx.x*64 + (t & 63);
  int m = blockIdx.y*4 + (t >> 6);
  if (n >= N) return;
  float acc = 0.f;
  const float* a = A + (size_t)m*K;
  const float* bp = B + n;
  #pragma unroll 8
  for (int k = 0; k < K; ++k) acc = fmaf(a[k], bp[(size_t)k*N], acc);
  acc += bias[n];
  if (act == 0) acc = fmaxf(acc, 0.f);
  else acc = 1.f/(1.f + expf(-acc));
  C[(size_t)m*N + n] = acc;
}

extern "C" void kernel_launch(void* const* d_in, const int* in_sizes, int n_in,
                              void* d_out, int out_size, void* d_ws, size_t ws_size,
                              hipStream_t stream) {
  const float* image   = (const float*)d_in[0];
  const int*   target  = (const int*)d_in[1];
  const float* conv1_w = (const float*)d_in[2];
  const float* conv1_b = (const float*)d_in[3];
  const float* conv2_w = (const float*)d_in[4];
  const float* conv2_b = (const float*)d_in[5];
  const float* Wm      = (const float*)d_in[6];
  const float* d1_w    = (const float*)d_in[7];
  const float* d1_b    = (const float*)d_in[8];
  const float* d2_w    = (const float*)d_in[9];
  const float* d2_b    = (const float*)d_in[10];
  const float* d3_w    = (const float*)d_in[11];
  const float* d3_b    = (const float*)d_in[12];

  char* ws = (char*)d_ws;
  unsigned short* in1h = (unsigned short*)(ws);               // +IN1_ELEMS: in1l
  unsigned short* BTh  = (unsigned short*)(ws + 104857600);   // +BT_ELEMS: BTl
  float* c2out  = (float*)(ws + 126091264);                   // 9437184 B
  float* pc     = (float*)(ws + 135528448);                   // 9437184 B
  float* s1     = (float*)(ws + 144965632);                   // 163840 B
  float* s2     = (float*)(ws + 145129472);                   // 163840 B (contiguous after s1)
  float* masked = (float*)(ws + 145293312);                   // 163840 B
  float* h1     = (float*)(ws + 145457152);                   // 524288 B
  float* h2     = (float*)(ws + 145981440);                   // 1048576 B

  float* out_norm = (float*)d_out;            // 2560
  float* out_pred = out_norm + 2560;          // 256
  float* dec      = out_norm + 2816;          // 200704

  wt_kernel<<<dim3(324,4),256,0,stream>>>(conv2_w, BTh, BTh + BT_ELEMS, c2out);
  conv1_kernel<<<dim3(20,256),256,0,stream>>>(image, conv1_w, conv1_b, in1h, in1h + IN1_ELEMS);
  conv2_mfma<<<dim3(2,72,8),256,0,stream>>>(in1h, BTh, c2out);
  squash_pc_kernel<<<dim3(1152),256,0,stream>>>(c2out, conv2_b, pc, s1);
  s1_producer<<<dim3(72,16),256,0,stream>>>(pc, Wm, s1);
  routing2<<<dim3(36,32),320,0,stream>>>(pc, Wm, s1, s2);
  finalize_kernel<<<dim3(256),64,0,stream>>>(s2, target, out_norm, out_pred, masked);
  dec_gemm<<<dim3(8,64),256,0,stream>>>(masked, d1_w, d1_b, h1, 160, 512, 0);
  dec_gemm<<<dim3(16,64),256,0,stream>>>(h1, d2_w, d2_b, h2, 512, 1024, 0);
  dec_gemm<<<dim3(13,64),256,0,stream>>>(h2, d3_w, d3_b, dec, 1024, 784, 1);
}

// Round 7
// 633.367 us; speedup vs baseline: 1.5330x; 1.1631x over previous
//
#include <hip/hip_runtime.h>
#include <math.h>

#define EPS 1e-7f
#define IN1_ELEMS 26214400   // 256*20*20*256 (fp16 elements, single plane)
#define BT_ELEMS  5308416    // 256*20736 (per fp16 plane)

typedef float fvec4 __attribute__((ext_vector_type(4)));
typedef short short8 __attribute__((ext_vector_type(8)));
typedef _Float16 half8 __attribute__((ext_vector_type(8)));

__device__ inline unsigned short f2h(float f){
  _Float16 h = (_Float16)f;
  return __builtin_bit_cast(unsigned short, h);
}
__device__ inline float h2f(unsigned short u){
  return (float)__builtin_bit_cast(_Float16, u);
}
__device__ inline void async16(unsigned short* dst, const unsigned short* src){
  __builtin_amdgcn_global_load_lds((const __attribute__((address_space(1))) void*)src,
                                   (__attribute__((address_space(3))) void*)dst, 16, 0, 0);
}
__device__ inline fvec4 mfma_f16(short8 a, short8 b, fvec4 c){
  return __builtin_amdgcn_mfma_f32_16x16x32_f16(
      __builtin_bit_cast(half8, a), __builtin_bit_cast(half8, b), c, 0, 0, 0);
}

// ---------------- K0: conv2_w -> BT^T (fp16 hi/lo, scaled x64) + zero c2out --------
// B scaled by 2^6 so the Bl residual plane stays in fp16-normal range; A plane is
// scaled by 2^-6 to compensate exactly.
__global__ __launch_bounds__(256) void wt_kernel(const float* __restrict__ w2,
    unsigned short* __restrict__ BTh, unsigned short* __restrict__ BTl,
    float* __restrict__ c2out){
  __shared__ float tile[64][65];
  int t = threadIdx.x;
  int k0 = blockIdx.x * 64, oc0 = blockIdx.y * 64;
  int bid = blockIdx.y*324 + blockIdx.x;
  for (int g = bid*256 + t; g < 2359296; g += 1296*256) c2out[g] = 0.f;
  #pragma unroll
  for (int p = 0; p < 16; ++p){
    int f = p*256 + t;
    int kr = f >> 6, cc = f & 63;
    tile[kr][cc] = w2[(size_t)(k0 + kr)*256 + oc0 + cc];
  }
  __syncthreads();
  #pragma unroll
  for (int p = 0; p < 16; ++p){
    int f = p*256 + t;
    int ocr = f >> 6, kc = f & 63;
    float v = tile[kc][ocr] * 64.f;
    unsigned short h = f2h(v);
    size_t idx = (size_t)(oc0 + ocr)*20736 + k0 + kc;
    BTh[idx] = h;
    BTl[idx] = f2h(v - h2f(h));
  }
}

// ---------------- K1: conv1 9x9 s1 + bias + relu -> fp16 (x 2^-6) ----------------
__global__ __launch_bounds__(256) void conv1_kernel(const float* __restrict__ img,
    const float* __restrict__ w1, const float* __restrict__ b1,
    unsigned short* __restrict__ outh){
  __shared__ float sim[252];
  int t = threadIdx.x;
  int oh = blockIdx.x, b = blockIdx.y;
  if (t < 252) sim[t] = img[((size_t)b*28 + oh + t/28)*28 + (t%28)];
  __syncthreads();
  float acc[20];
  #pragma unroll
  for (int i = 0; i < 20; ++i) acc[i] = 0.f;
  #pragma unroll
  for (int kh = 0; kh < 9; ++kh){
    float im[28];
    #pragma unroll
    for (int c = 0; c < 28; ++c) im[c] = sim[kh*28 + c];
    #pragma unroll
    for (int kw = 0; kw < 9; ++kw){
      float wv = w1[(kh*9 + kw)*256 + t];
      #pragma unroll
      for (int ow = 0; ow < 20; ++ow) acc[ow] = fmaf(im[ow + kw], wv, acc[ow]);
    }
  }
  float bv = b1[t];
  size_t base = ((size_t)(b*20 + oh))*20*256 + t;
  #pragma unroll
  for (int ow = 0; ow < 20; ++ow){
    float v = fmaxf(acc[ow] + bv, 0.f);
    outh[base + ow*256] = f2h(v * 0.015625f);   // x 2^-6
  }
}

// ---------------- K2: conv2 implicit GEMM, fp16 2-pass MFMA ----------------
// A fp16 single plane (x2^-6); B fp16 hi+lo (x2^6); acc = A*Bh + A*Bl (exact scale
// cancellation). Double-buffered single-barrier pipeline; XOR-swizzled LDS
// positions -> fragment ds_read_b128 2-way-only. 48 KB LDS -> 3 blocks/CU.
__global__ __launch_bounds__(256) void conv2_mfma(const unsigned short* __restrict__ in1h,
    const unsigned short* __restrict__ BTh, float* __restrict__ out){
  __shared__ __align__(16) unsigned short lds[24576]; // 2 bufs x (A|Bh|Bl 4096 shorts each)
  const int t = threadIdx.x;
  const int lane = t & 63, w = t >> 6;
  const int m0 = blockIdx.y * 128, n0 = blockIdx.x * 128;
  const int rowA = t >> 2, q = (t & 3) ^ ((t >> 3) & 3);

  const unsigned short* aS[2];
  const unsigned short* bS[2];
  #pragma unroll
  for (int h = 0; h < 2; ++h){
    int m = m0 + h*64 + rowA;
    int bb = m / 36, s = m - bb*36, oh = s / 6, ow = s - oh*6;
    aS[h] = in1h + ((size_t)((bb*20 + 2*oh)*20 + 2*ow))*256 + q*8;
    int n = n0 + h*64 + rowA;
    bS[h] = BTh + (size_t)n*20736 + q*8;
  }

  const int r = lane & 15;
  const int p = (lane >> 4) ^ ((lane >> 1) & 3);
  int roA[4], roB[4];
  #pragma unroll
  for (int i=0;i<4;++i){
    roA[i] = ((w >> 1)*64 + i*16 + r)*32 + p*8;
    roB[i] = ((w & 1)*64  + i*16 + r)*32 + p*8;
  }

  fvec4 acc[4][4];
  #pragma unroll
  for (int i=0;i<4;++i)
    #pragma unroll
    for (int j=0;j<4;++j) acc[i][j] = (fvec4){0.f,0.f,0.f,0.f};

  const int ks0 = blockIdx.z * 81;

  #define STAGE(BUF, KS) do{                                            \
    int kk_ = (KS) >> 3, kh_ = kk_/9, kw_ = kk_ - kh_*9;                \
    int aoff_ = (kh_*20 + kw_)*256 + ((KS) & 7)*32;                     \
    int boff_ = (KS)*32;                                                \
    int base_ = (BUF)*12288;                                            \
    _Pragma("unroll")                                                   \
    for (int h_=0; h_<2; ++h_){                                         \
      async16(&lds[base_ +        h_*2048 + t*8], aS[h_] + aoff_);      \
      async16(&lds[base_ + 4096 + h_*2048 + t*8], bS[h_] + boff_);      \
      async16(&lds[base_ + 8192 + h_*2048 + t*8], bS[h_] + BT_ELEMS + boff_); \
    } }while(0)

  STAGE(0, ks0);
  int buf = 0;
  for (int it = 0; it < 81; ++it){
    __syncthreads();
    if (it < 80) STAGE(buf^1, ks0 + it + 1);
    int base = buf*12288;
    short8 af[4], bh[4], bl[4];
    #pragma unroll
    for (int i=0;i<4;++i){
      af[i] = *(const short8*)&lds[base + roA[i]];
      bh[i] = *(const short8*)&lds[base + 4096 + roB[i]];
      bl[i] = *(const short8*)&lds[base + 8192 + roB[i]];
    }
    #pragma unroll
    for (int i=0;i<4;++i)
      #pragma unroll
      for (int j=0;j<4;++j){
        acc[i][j] = mfma_f16(af[i], bh[j], acc[i][j]);
        acc[i][j] = mfma_f16(af[i], bl[j], acc[i][j]);
      }
    buf ^= 1;
  }

  const int qm = (w >> 1)*64, qn = (w & 1)*64;
  #pragma unroll
  for (int i=0;i<4;++i){
    int gm = m0 + qm + i*16 + ((lane >> 4) << 2);
    #pragma unroll
    for (int j=0;j<4;++j){
      int gn = n0 + qn + j*16 + (lane & 15);
      #pragma unroll
      for (int rr=0;rr<4;++rr)
        atomicAdd(&out[(size_t)(gm + rr)*256 + gn], acc[i][j][rr]);
    }
  }
}

// ---------------- K3: bias + relu + squash -> pc ; + zero s1/s2 ----------------
__global__ __launch_bounds__(256) void squash_pc_kernel(const float* __restrict__ c2out,
    const float* __restrict__ b2, float* __restrict__ pc, float* __restrict__ s1s2){
  int g = blockIdx.x*256 + threadIdx.x;   // 294912 capsules
  if (g < 81920) s1s2[g] = 0.f;           // zero s1+s2 (contiguous) before atomics
  const float* s = c2out + (size_t)g*8;
  int oc0 = (g & 31) * 8;
  float v[8], sq = 0.f;
  #pragma unroll
  for (int e=0;e<8;++e){ float x = fmaxf(s[e] + b2[oc0+e], 0.f); v[e] = x; sq += x*x; }
  float fac = sq / ((1.f + sq) * sqrtf(sq + EPS));
  float* o = pc + (size_t)g*8;
  #pragma unroll
  for (int e=0;e<8;++e) o[e] = v[e]*fac;
}

// ---------------- K4a: s1 partials only (u_hat recomputed later, never stored) --------
__global__ __launch_bounds__(256) void s1_producer(const float* __restrict__ pc,
    const float* __restrict__ Wm, float* __restrict__ s1){
  __shared__ float pcl[2048]; // [16 b][16 n][8 i]
  int t = threadIdx.x;
  int n0 = blockIdx.x * 16, b0 = blockIdx.y * 16;
  #pragma unroll
  for (int p = 0; p < 8; ++p){
    int f = p*256 + t;
    int bl = f >> 7, rem = f & 127;
    pcl[f] = pc[((size_t)(b0 + bl)*1152 + n0)*8 + rem];
  }
  __syncthreads();
  for (int r = 0; r < 10; ++r){
    int item = r*256 + t;               // (b_local, cj)
    int bl = item / 160, cj = item - bl*160;
    float s1a = 0.f;
    const float* pb = &pcl[bl*128];
    #pragma unroll 4
    for (int nl = 0; nl < 16; ++nl){
      const float4* wp = (const float4*)&Wm[((size_t)(n0 + nl)*160 + cj)*8];
      float4 w0 = wp[0], w1 = wp[1];
      const float4* pp = (const float4*)&pb[nl*8];
      float4 p0 = pp[0], p1 = pp[1];
      s1a += w0.x*p0.x + w0.y*p0.y + w0.z*p0.z + w0.w*p0.w
           + w1.x*p1.x + w1.y*p1.y + w1.z*p1.z + w1.w*p1.w;
    }
    atomicAdd(&s1[(b0 + bl)*160 + cj], s1a);
  }
}

// ---------------- K4b: fused routing: recompute u_hat -> uv -> softmax -> s2 ----------
__global__ __launch_bounds__(320) void routing2(const float* __restrict__ pc,
    const float* __restrict__ Wm, const float* __restrict__ s1, float* __restrict__ s2){
  __shared__ float pcl[32][64];     // [nl][b*8+i]
  __shared__ float v1l[8][160];
  __shared__ float facl[80];
  __shared__ float c2l[32][10][8];  // [nl][c][b]: uv, then softmax'd c2
  const int t = threadIdx.x;
  const int n0 = blockIdx.x*32, b0 = blockIdx.y*8;

  for (int f = t; f < 2048; f += 320){
    int b = f >> 8, rem = f & 255;            // rem = nl*8+i
    pcl[rem >> 3][b*8 + (rem & 7)] =
        pc[((size_t)(b0 + b)*1152 + n0 + (rem >> 3))*8 + (rem & 7)];
  }
  if (t < 80){
    int b = t/10, c = t - (t/10)*10;
    const float* s = s1 + (size_t)(b0 + b)*160 + c*16;
    float sq = 0.f;
    #pragma unroll
    for (int j=0;j<16;++j){ float v = s[j]*0.1f; sq += v*v; }
    facl[t] = 0.1f * sq / ((1.f + sq) * sqrtf(sq + EPS));
  }
  __syncthreads();
  for (int f = t; f < 1280; f += 320){
    int b = f / 160, cj = f - b*160;
    v1l[b][cj] = s1[(size_t)(b0 + b)*160 + cj] * facl[b*10 + (cj >> 4)];
  }
  __syncthreads();

  // ---- pass 1: uv.  thread = (nl, c) ----
  {
    const int nl = t / 10, c = t - (t/10)*10;
    float pcr[64];
    #pragma unroll
    for (int u = 0; u < 16; ++u) ((float4*)pcr)[u] = ((const float4*)&pcl[nl][0])[u];
    const float* wrow = Wm + ((size_t)(n0 + nl)*160 + c*16)*8;
    float uv[8];
    #pragma unroll
    for (int b=0;b<8;++b) uv[b] = 0.f;
    #pragma unroll
    for (int j = 0; j < 16; ++j){
      float4 w0 = ((const float4*)wrow)[j*2], w1 = ((const float4*)wrow)[j*2+1];
      #pragma unroll
      for (int b=0;b<8;++b){
        float tj = w0.x*pcr[b*8+0] + w0.y*pcr[b*8+1] + w0.z*pcr[b*8+2] + w0.w*pcr[b*8+3]
                 + w1.x*pcr[b*8+4] + w1.y*pcr[b*8+5] + w1.z*pcr[b*8+6] + w1.w*pcr[b*8+7];
        uv[b] = fmaf(tj, v1l[b][c*16 + j], uv[b]);
      }
    }
    #pragma unroll
    for (int b=0;b<8;++b) c2l[nl][c][b] = uv[b];
  }
  __syncthreads();

  // ---- softmax over c: thread = (nl, b) ----
  if (t < 256){
    int snl = t >> 3, sb = t & 7;
    float mx = c2l[snl][0][sb];
    #pragma unroll
    for (int cc=1;cc<10;++cc) mx = fmaxf(mx, c2l[snl][cc][sb]);
    float e[10], sum = 0.f;
    #pragma unroll
    for (int cc=0;cc<10;++cc){ e[cc] = expf(c2l[snl][cc][sb] - mx); sum += e[cc]; }
    float inv = 1.f/sum;
    #pragma unroll
    for (int cc=0;cc<10;++cc) c2l[snl][cc][sb] = e[cc]*inv;
  }
  __syncthreads();

  // ---- pass 3: s2.  thread = (b-quad g, cj); owns 4 accumulators, zero LDS atomics ----
  {
    const int g = t / 160, cj = t - g*160;   // g in {0,1}
    const int c = cj >> 4;
    float acc0 = 0.f, acc1 = 0.f, acc2 = 0.f, acc3 = 0.f;
    for (int nl = 0; nl < 32; ++nl){
      const float4* wp = (const float4*)&Wm[((size_t)(n0 + nl)*160 + cj)*8];
      float4 w0 = wp[0], w1 = wp[1];
      const float* pb = &pcl[nl][g*32];
      const float* cc = &c2l[nl][c][g*4];
      float4 p0, p1;
      p0 = ((const float4*)pb)[0]; p1 = ((const float4*)pb)[1];
      acc0 = fmaf(cc[0], w0.x*p0.x + w0.y*p0.y + w0.z*p0.z + w0.w*p0.w
                       + w1.x*p1.x + w1.y*p1.y + w1.z*p1.z + w1.w*p1.w, acc0);
      p0 = ((const float4*)pb)[2]; p1 = ((const float4*)pb)[3];
      acc1 = fmaf(cc[1], w0.x*p0.x + w0.y*p0.y + w0.z*p0.z + w0.w*p0.w
                       + w1.x*p1.x + w1.y*p1.y + w1.z*p1.z + w1.w*p1.w, acc1);
      p0 = ((const float4*)pb)[4]; p1 = ((const float4*)pb)[5];
      acc2 = fmaf(cc[2], w0.x*p0.x + w0.y*p0.y + w0.z*p0.z + w0.w*p0.w
                       + w1.x*p1.x + w1.y*p1.y + w1.z*p1.z + w1.w*p1.w, acc2);
      p0 = ((const float4*)pb)[6]; p1 = ((const float4*)pb)[7];
      acc3 = fmaf(cc[3], w0.x*p0.x + w0.y*p0.y + w0.z*p0.z + w0.w*p0.w
                       + w1.x*p1.x + w1.y*p1.y + w1.z*p1.z + w1.w*p1.w, acc3);
    }
    atomicAdd(&s2[(size_t)(b0 + g*4 + 0)*160 + cj], acc0);
    atomicAdd(&s2[(size_t)(b0 + g*4 + 1)*160 + cj], acc1);
    atomicAdd(&s2[(size_t)(b0 + g*4 + 2)*160 + cj], acc2);
    atomicAdd(&s2[(size_t)(b0 + g*4 + 3)*160 + cj], acc3);
  }
}

// ---------------- K4d: v2, norms, argmax, mask ----------------
__global__ __launch_bounds__(64) void finalize_kernel(const float* __restrict__ s2,
    const int* __restrict__ target, float* __restrict__ out_norm,
    float* __restrict__ out_pred, float* __restrict__ masked){
  __shared__ float v2l[160];
  __shared__ float nrm[10];
  int b = blockIdx.x, t = threadIdx.x;
  if (t < 10){
    const float* s = s2 + b*160 + t*16;
    float x[16], sq = 0.f;
    #pragma unroll
    for (int j=0;j<16;++j){ x[j] = s[j]; sq += x[j]*x[j]; }
    float fac = sq / ((1.f + sq) * sqrtf(sq + EPS));
    float n2 = 0.f;
    #pragma unroll
    for (int j=0;j<16;++j){ float v = x[j]*fac; v2l[t*16+j] = v; n2 += v*v; }
    float nr = sqrtf(n2 + EPS);
    nrm[t] = nr;
    out_norm[b*10 + t] = nr;
  }
  __syncthreads();
  if (t == 0){
    int am = 0; float bv = nrm[0];
    #pragma unroll
    for (int c=1;c<10;++c) if (nrm[c] > bv){ bv = nrm[c]; am = c; }
    out_pred[b] = (float)am;
  }
  int tg = target[b];
  #pragma unroll
  for (int p = 0; p < 3; ++p){
    int cj = p*64 + t;
    if (cj < 160) masked[b*160 + cj] = ((cj >> 4) == tg) ? v2l[cj] : 0.f;
  }
}

// ---------------- decoder GEMMs (M=256 fixed) ----------------
__global__ __launch_bounds__(256) void dec_gemm(const float* __restrict__ A,
    const float* __restrict__ B, const float* __restrict__ bias, float* __restrict__ C,
    int K, int N, int act){
  int t = threadIdx.x;
  int n = blockIdx.x*64 + (t & 63);
  int m = blockIdx.y*4 + (t >> 6);
  if (n >= N) return;
  float acc = 0.f;
  const float* a = A + (size_t)m*K;
  const float* bp = B + n;
  #pragma unroll 8
  for (int k = 0; k < K; ++k) acc = fmaf(a[k], bp[(size_t)k*N], acc);
  acc += bias[n];
  if (act == 0) acc = fmaxf(acc, 0.f);
  else acc = 1.f/(1.f + expf(-acc));
  C[(size_t)m*N + n] = acc;
}

extern "C" void kernel_launch(void* const* d_in, const int* in_sizes, int n_in,
                              void* d_out, int out_size, void* d_ws, size_t ws_size,
                              hipStream_t stream) {
  const float* image   = (const float*)d_in[0];
  const int*   target  = (const int*)d_in[1];
  const float* conv1_w = (const float*)d_in[2];
  const float* conv1_b = (const float*)d_in[3];
  const float* conv2_w = (const float*)d_in[4];
  const float* conv2_b = (const float*)d_in[5];
  const float* Wm      = (const float*)d_in[6];
  const float* d1_w    = (const float*)d_in[7];
  const float* d1_b    = (const float*)d_in[8];
  const float* d2_w    = (const float*)d_in[9];
  const float* d2_b    = (const float*)d_in[10];
  const float* d3_w    = (const float*)d_in[11];
  const float* d3_b    = (const float*)d_in[12];

  char* ws = (char*)d_ws;
  unsigned short* in1h = (unsigned short*)(ws);               // fp16, 52428800 B
  unsigned short* BTh  = (unsigned short*)(ws + 52428800);    // fp16 hi; +BT_ELEMS: lo
  float* c2out  = (float*)(ws + 73662464);                    // 9437184 B
  float* pc     = (float*)(ws + 83099648);                    // 9437184 B
  float* s1     = (float*)(ws + 92536832);                    // 163840 B
  float* s2     = (float*)(ws + 92700672);                    // 163840 B (contiguous after s1)
  float* masked = (float*)(ws + 92864512);                    // 163840 B
  float* h1     = (float*)(ws + 93028352);                    // 524288 B
  float* h2     = (float*)(ws + 93552640);                    // 1048576 B

  float* out_norm = (float*)d_out;            // 2560
  float* out_pred = out_norm + 2560;          // 256
  float* dec      = out_norm + 2816;          // 200704

  wt_kernel<<<dim3(324,4),256,0,stream>>>(conv2_w, BTh, BTh + BT_ELEMS, c2out);
  conv1_kernel<<<dim3(20,256),256,0,stream>>>(image, conv1_w, conv1_b, in1h);
  conv2_mfma<<<dim3(2,72,8),256,0,stream>>>(in1h, BTh, c2out);
  squash_pc_kernel<<<dim3(1152),256,0,stream>>>(c2out, conv2_b, pc, s1);
  s1_producer<<<dim3(72,16),256,0,stream>>>(pc, Wm, s1);
  routing2<<<dim3(36,32),320,0,stream>>>(pc, Wm, s1, s2);
  finalize_kernel<<<dim3(256),64,0,stream>>>(s2, target, out_norm, out_pred, masked);
  dec_gemm<<<dim3(8,64),256,0,stream>>>(masked, d1_w, d1_b, h1, 160, 512, 0);
  dec_gemm<<<dim3(16,64),256,0,stream>>>(h1, d2_w, d2_b, h2, 512, 1024, 0);
  dec_gemm<<<dim3(13,64),256,0,stream>>>(h2, d3_w, d3_b, dec, 1024, 784, 1);
}